// Round 10
// baseline (175.204 us; speedup 1.0000x reference)
//
#include <hip/hip_runtime.h>
#include <hip/hip_bf16.h>
#include <math.h>

// Problem constants (AttentionSynapse): B=2, Tq=Tk=2048, E=Eq=Ek=1024, H=16, D=64
#define B_    2
#define TQ    2048
#define TK    2048
#define E_    1024
#define MTOT  4096   // B*TQ

typedef __attribute__((ext_vector_type(8))) short bf16x8;
typedef __attribute__((ext_vector_type(4))) float f32x4;

__device__ __forceinline__ unsigned short f2bf(float x) {
  unsigned int u = __float_as_uint(x);
  u += 0x7fff + ((u >> 16) & 1);      // round-to-nearest-even
  return (unsigned short)(u >> 16);
}

__device__ __forceinline__ void load_lds16(const void* g, void* l) {
  // async global->LDS, 16B/lane; LDS dest = wave-uniform base + lane*16
  __builtin_amdgcn_global_load_lds(
      (const __attribute__((address_space(1))) unsigned int*)g,
      (__attribute__((address_space(3))) unsigned int*)l, 16, 0, 0);
}

#define BARRIER() do { asm volatile("" ::: "memory"); __builtin_amdgcn_s_barrier(); asm volatile("" ::: "memory"); } while (0)
#define WAIT_VM12()  asm volatile("s_waitcnt vmcnt(12)" ::: "memory")
#define WAIT_VM0()   asm volatile("s_waitcnt vmcnt(0)" ::: "memory")

// ---------------------------------------------------------------------------
// B-tile stage: 128 rows x 64 cols bf16 (16 KiB), 256 threads x 4 gload_lds.
// T2 swizzle: logical (row, byte o) -> LDS byte row*128 + (o ^ ((row&7)<<4));
// LDS dest linear, global source col pre-XOR'd (involution), read applies XOR.
// ---------------------------------------------------------------------------
__device__ __forceinline__ void stage_B(const unsigned short* gsrc, unsigned short* lds,
                                        int tid, int kt) {
  const int r  = tid >> 3;                          // 0..31
  const int c8 = ((tid & 7) ^ (r & 7)) * 8;         // pre-swizzled col (elems)
  const unsigned short* g = gsrc + (size_t)r * E_ + (size_t)kt * 64 + c8;
  unsigned short* l = lds + tid * 8;
#pragma unroll
  for (int i = 0; i < 4; ++i)                       // rows r, r+32, r+64, r+96
    load_lds16(g + (size_t)(32 * i) * E_, l + 2048 * i);
}

// Swizzled LDS read address (elems): row in tile, o = byte offset in row
#define LDS_AT(base, row, o) ((const bf16x8*)((base) + (((row) * 128 + ((o) ^ (((row) & 7) << 4))) >> 1)))

// A fragments: DIRECT global->reg (bf16x8 = global_load_dwordx4). Same frag
// indexing as the LDS path: row = wm*64+f*16+li16, k = kt*64 + ks*32 + hi4*8.
#define LOAD_A(dst, kt)                                                       \
  do {                                                                        \
    _Pragma("unroll") for (int f = 0; f < 4; ++f)                             \
      _Pragma("unroll") for (int ks = 0; ks < 2; ++ks)                        \
        dst[f][ks] = *(const bf16x8*)(Ag + (size_t)(wm * 64 + f * 16 + li16) * E_ \
                                         + (size_t)(kt) * 64 + ks * 32 + hi4 * 8); \
  } while (0)

#define READ_B()                                                              \
  do {                                                                        \
    _Pragma("unroll") for (int g = 0; g < 4; ++g)                             \
      _Pragma("unroll") for (int ks = 0; ks < 2; ++ks)                        \
        b[g][ks] = *LDS_AT(Bc, wn * 64 + g * 16 + li16, ks * 64 + hi4 * 16);  \
  } while (0)

#define MFMA_ALL(av)                                                          \
  do {                                                                        \
    __builtin_amdgcn_s_setprio(1);                                            \
    _Pragma("unroll") for (int ks = 0; ks < 2; ++ks)                          \
      _Pragma("unroll") for (int f = 0; f < 4; ++f)                           \
        _Pragma("unroll") for (int g = 0; g < 4; ++g)                         \
          acc[f][g] = __builtin_amdgcn_mfma_f32_16x16x32_bf16(                \
              av[f][ks], b[g][ks], acc[f][g], 0, 0, 0);                       \
    __builtin_amdgcn_s_setprio(0);                                            \
  } while (0)

// One half-tile step: issue next-A (regs) + B(t+2) stage, read B(t), MFMA,
// counted vmcnt(12) = younger-than-B(t+1) set {A(t+1)[8], B(t+2)[4]} exactly,
// one barrier. Slot s0 = t%3 read; s2 = (t+2)%3 staged; (t+2)%3 == (t-1)%3,
// whose ds_reads all retired before the (t-1)-end barrier -> no hazard.
#define HALF_STEP(acur, anext, t)                                             \
  do {                                                                        \
    LOAD_A(anext, ((t) + 1) & 15);                                            \
    stage_B(Bg, Bsl[s2], tid, ((t) + 2) & 15);                                \
    const unsigned short* Bc = Bsl[s0];                                       \
    READ_B();                                                                 \
    MFMA_ALL(acur);                                                           \
    WAIT_VM12();                                                              \
    BARRIER();                                                                \
    s0 = (s0 == 2) ? 0 : s0 + 1;                                              \
    s2 = (s2 == 2) ? 0 : s2 + 1;                                              \
  } while (0)

// Prologue issue order B(0), A(0), B(1): drain B(0) keeping {A(0)[8],B(1)[4]}
// = vmcnt(12), matching the steady-state invariant at each tile start.
#define GEMM_PIPELINE()                                                       \
  do {                                                                        \
    stage_B(Bg, Bsl[0], tid, 0);                                              \
    LOAD_A(aA, 0);                                                            \
    stage_B(Bg, Bsl[1], tid, 1);                                              \
    WAIT_VM12();                                                              \
    BARRIER();                                                                \
    int s0 = 0, s2 = 2;                                                       \
    _Pragma("unroll 1") for (int it = 0; it < 8; ++it) {                      \
      HALF_STEP(aA, aB, 2 * it);                                              \
      HALF_STEP(aB, aA, 2 * it + 1);                                          \
    }                                                                         \
  } while (0)

// ---------------------------------------------------------------------------
// prep: bf16-cast gq, gk, WK; scale WQ rows by Wmix[head] then cast.
// ---------------------------------------------------------------------------
__global__ void prep_kernel(const float* __restrict__ gq, const float* __restrict__ gk,
                            const float* __restrict__ WQ, const float* __restrict__ WK,
                            const float* __restrict__ Wmix,
                            unsigned short* __restrict__ gqb, unsigned short* __restrict__ gkb,
                            unsigned short* __restrict__ wqb, unsigned short* __restrict__ wkb) {
  const int NGQ = (B_ * TQ * E_) / 4;   // 1048576 vec4
  const int NW  = (E_ * E_) / 4;        // 262144 vec4
  const int total = 2 * NGQ + 2 * NW;
  for (int idx = blockIdx.x * blockDim.x + threadIdx.x; idx < total;
       idx += gridDim.x * blockDim.x) {
    const float4* src; unsigned short* dst; int local; float scale = 1.0f;
    if (idx < NGQ)            { src = (const float4*)gq; dst = gqb; local = idx; }
    else if (idx < 2 * NGQ)   { src = (const float4*)gk; dst = gkb; local = idx - NGQ; }
    else if (idx < 2*NGQ+NW)  { src = (const float4*)WQ; dst = wqb; local = idx - 2*NGQ;
                                scale = Wmix[local >> 14]; }   // vec4 idx -> row e = local/256, head = e/64
    else                      { src = (const float4*)WK; dst = wkb; local = idx - 2*NGQ - NW; }
    float4 v = src[local];
    ushort4 o;
    o.x = f2bf(v.x * scale); o.y = f2bf(v.y * scale);
    o.z = f2bf(v.z * scale); o.w = f2bf(v.w * scale);
    ((ushort4*)dst)[local] = o;
  }
}

// ---------------------------------------------------------------------------
// Projection GEMM: C[m,n] = sum_k A[m,k]*W[n,k]. 128x128 tile, 4 waves,
// A direct-to-reg, B via LDS ring. grid 512 (1-D, XCD rect decode), 2/CU.
// A has 4096 rows per side -> 32 m-tiles of 128. Per XCD (64 blocks):
// side=xcd>>2, rect=xcd&3 -> 8 mt x 8 nt panels = 2+2 MB = one XCD L2.
// ---------------------------------------------------------------------------
__global__ __launch_bounds__(256, 2) void proj_kernel(
    const unsigned short* __restrict__ gqb, const unsigned short* __restrict__ gkb,
    const unsigned short* __restrict__ wqb, const unsigned short* __restrict__ wkb,
    unsigned short* __restrict__ qp, unsigned short* __restrict__ kp) {
  __shared__ __align__(16) unsigned short Bsl[3][8192];    // 3 x (128x64) = 48 KiB
  const int g_  = blockIdx.x;
  const int xcd = g_ & 7, j = g_ >> 3;      // j in 0..63
  const int side = xcd >> 2, r_ = xcd & 3;
  const int mt = r_ * 8 + (j & 7);          // 0..31  (32 x 128 = 4096 rows)
  const int nt = j >> 3;                    // 0..7
  const int m0 = mt * 128, n0 = nt * 128;
  const unsigned short* Ag = (side ? gkb : gqb) + (size_t)m0 * E_;
  const unsigned short* Bg = (side ? wkb : wqb) + (size_t)n0 * E_;
  unsigned short* C        = (side ? kp  : qp);
  const int tid = threadIdx.x, wave = tid >> 6, lane = tid & 63;
  const int wm = wave >> 1, wn = wave & 1, li16 = lane & 15, hi4 = lane >> 4;
  f32x4 acc[4][4] = {};
  bf16x8 aA[4][2], aB[4][2];
  bf16x8 b[4][2];
  GEMM_PIPELINE();
#pragma unroll
  for (int f = 0; f < 4; ++f)
#pragma unroll
    for (int g = 0; g < 4; ++g)
#pragma unroll
      for (int j2 = 0; j2 < 4; ++j2) {
        int row = m0 + wm * 64 + f * 16 + hi4 * 4 + j2;
        int col = n0 + wn * 64 + g * 16 + li16;
        C[(size_t)row * E_ + col] = f2bf(acc[f][g][j2]);
      }
  WAIT_VM0();   // drain wrapped tail stages before endpgm
}

// ---------------------------------------------------------------------------
// Score GEMM + fused partial logsumexp. 128x128 tile, 4 waves, A-direct.
// grid 512 (1-D): 2 blocks/CU. XCD rect: bb=xcd>>2, rect=xcd&3 ->
// qt in [(r&1)*8,+8), kt in [(r>>1)*8,+8); per-XCD set 2+2 MB = L2-fit.
// partials stride 16 (kt 0..15).
// ---------------------------------------------------------------------------
__global__ __launch_bounds__(256, 2) void score_lse_kernel(
    const unsigned short* __restrict__ qp, const unsigned short* __restrict__ kp,
    float2* __restrict__ partials) {
  __shared__ __align__(16) unsigned short Bsl[3][8192];
  __shared__ float redM[2][128];
  __shared__ float redS[2][128];
  const int g_  = blockIdx.x;
  const int xcd = g_ & 7, j = g_ >> 3;      // j in 0..63
  const int bb = xcd >> 2, r_ = xcd & 3;
  const int qt = (r_ & 1) * 8 + (j & 7);    // 0..15
  const int kt = (r_ >> 1) * 8 + (j >> 3);  // 0..15
  const int m0 = qt * 128, n0 = kt * 128;
  const unsigned short* Ag = qp + (size_t)bb * TQ * E_ + (size_t)m0 * E_;
  const unsigned short* Bg = kp + (size_t)bb * TK * E_ + (size_t)n0 * E_;
  const int tid = threadIdx.x, wave = tid >> 6, lane = tid & 63;
  const int wm = wave >> 1, wn = wave & 1, li16 = lane & 15, hi4 = lane >> 4;
  f32x4 acc[4][4] = {};
  bf16x8 aA[4][2], aB[4][2];
  bf16x8 b[4][2];
  GEMM_PIPELINE();
  // ---- per-row LSE partial over this block's 128 cols ----
  // lane holds rows wm*64 + f*16 + hi4*4 + j2 ; cols wn*64 + g*16 + li16
#pragma unroll
  for (int f = 0; f < 4; ++f) {
#pragma unroll
    for (int j2 = 0; j2 < 4; ++j2) {
      float m = fmaxf(fmaxf(acc[f][0][j2], acc[f][1][j2]),
                      fmaxf(acc[f][2][j2], acc[f][3][j2]));
#pragma unroll
      for (int msk = 1; msk < 16; msk <<= 1) m = fmaxf(m, __shfl_xor(m, msk, 64));
      float s = 0.f;
#pragma unroll
      for (int g = 0; g < 4; ++g) s += expf(acc[f][g][j2] - m);
#pragma unroll
      for (int msk = 1; msk < 16; msk <<= 1) s += __shfl_xor(s, msk, 64);
      if (li16 == 0) {
        int row = wm * 64 + f * 16 + hi4 * 4 + j2;   // 0..127 unique per (wm,f,hi4,j2)
        redM[wn][row] = m;
        redS[wn][row] = s;
      }
    }
  }
  __syncthreads();   // drains pending tail stages + makes red[] visible
  if (tid < 128) {
    float mA = redM[0][tid], mB = redM[1][tid];
    float M = fmaxf(mA, mB);
    float S = redS[0][tid] * expf(mA - M) + redS[1][tid] * expf(mB - M);
    int qrow = bb * TQ + m0 + tid;
    partials[(size_t)qrow * 16 + kt] = make_float2(M, S);
  }
}

// ---------------------------------------------------------------------------
// finalize: combine 16 (m,s) partials per q-row -> logsumexp
// ---------------------------------------------------------------------------
__global__ void finalize_kernel(const float2* __restrict__ partials, float* __restrict__ out) {
  int r = blockIdx.x * blockDim.x + threadIdx.x;
  if (r >= MTOT) return;
  const float2* p = partials + (size_t)r * 16;
  float M = p[0].x;
#pragma unroll
  for (int i = 1; i < 16; ++i) M = fmaxf(M, p[i].x);
  float S = 0.f;
#pragma unroll
  for (int i = 0; i < 16; ++i) S += p[i].y * expf(p[i].x - M);
  out[r] = logf(S) + M;
}

// ---------------------------------------------------------------------------
extern "C" void kernel_launch(void* const* d_in, const int* in_sizes, int n_in,
                              void* d_out, int out_size, void* d_ws, size_t ws_size,
                              hipStream_t stream) {
  const float* gq   = (const float*)d_in[0];
  const float* gk   = (const float*)d_in[1];
  const float* WQ   = (const float*)d_in[2];
  const float* WK   = (const float*)d_in[3];
  const float* Wmix = (const float*)d_in[4];
  float* out = (float*)d_out;

  char* ws = (char*)d_ws;
  unsigned short* gqb = (unsigned short*)(ws);                 // 8 MiB
  unsigned short* gkb = (unsigned short*)(ws + 8388608);       // 8 MiB
  unsigned short* wqb = (unsigned short*)(ws + 16777216);      // 2 MiB
  unsigned short* wkb = (unsigned short*)(ws + 18874368);      // 2 MiB
  unsigned short* qp  = (unsigned short*)(ws + 20971520);      // 8 MiB
  unsigned short* kp  = (unsigned short*)(ws + 29360128);      // 8 MiB
  float2* partials    = (float2*)(ws + 37748736);              // 512 KiB

  hipLaunchKernelGGL(prep_kernel, dim3(1024), dim3(256), 0, stream,
                     gq, gk, WQ, WK, Wmix, gqb, gkb, wqb, wkb);
  hipLaunchKernelGGL(proj_kernel, dim3(512), dim3(256), 0, stream,
                     gqb, gkb, wqb, wkb, qp, kp);
  hipLaunchKernelGGL(score_lse_kernel, dim3(512), dim3(256), 0, stream,
                     qp, kp, partials);
  hipLaunchKernelGGL(finalize_kernel, dim3(16), dim3(256), 0, stream,
                     partials, out);
}

// Round 11
// 171.875 us; speedup vs baseline: 1.0194x; 1.0194x over previous
//
#include <hip/hip_runtime.h>
#include <hip/hip_bf16.h>
#include <math.h>

// Problem constants (AttentionSynapse): B=2, Tq=Tk=2048, E=Eq=Ek=1024, H=16, D=64
#define B_    2
#define TQ    2048
#define TK    2048
#define E_    1024
#define MTOT  4096   // B*TQ

typedef __attribute__((ext_vector_type(8))) short bf16x8;
typedef __attribute__((ext_vector_type(4))) float f32x4;

__device__ __forceinline__ unsigned short f2bf(float x) {
  unsigned int u = __float_as_uint(x);
  u += 0x7fff + ((u >> 16) & 1);      // round-to-nearest-even
  return (unsigned short)(u >> 16);
}

__device__ __forceinline__ void load_lds16(const void* g, void* l) {
  // async global->LDS, 16B/lane; LDS dest = wave-uniform base + lane*16
  __builtin_amdgcn_global_load_lds(
      (const __attribute__((address_space(1))) unsigned int*)g,
      (__attribute__((address_space(3))) unsigned int*)l, 16, 0, 0);
}

#define BARRIER() do { asm volatile("" ::: "memory"); __builtin_amdgcn_s_barrier(); asm volatile("" ::: "memory"); } while (0)
#define WAIT_VM8()   asm volatile("s_waitcnt vmcnt(8)" ::: "memory")
#define WAIT_VM0()   asm volatile("s_waitcnt vmcnt(0)" ::: "memory")

// ---------------------------------------------------------------------------
// Tile stage: 128 rows x 64 cols bf16 (16 KiB), 256 threads x 4 gload_lds.
// T2 swizzle: logical (row, byte o) -> LDS byte row*128 + (o ^ ((row&7)<<4));
// LDS dest linear, global source col pre-XOR'd (involution), read applies XOR.
// ---------------------------------------------------------------------------
__device__ __forceinline__ void stage_T(const unsigned short* gsrc, unsigned short* lds,
                                        int tid, int kt) {
  const int r  = tid >> 3;                          // 0..31
  const int c8 = ((tid & 7) ^ (r & 7)) * 8;         // pre-swizzled col (elems)
  const unsigned short* g = gsrc + (size_t)r * E_ + (size_t)kt * 64 + c8;
  unsigned short* l = lds + tid * 8;
#pragma unroll
  for (int i = 0; i < 4; ++i)                       // rows r, r+32, r+64, r+96
    load_lds16(g + (size_t)(32 * i) * E_, l + 2048 * i);
}

// Swizzled LDS read address (elems): row in tile, o = byte offset in row
#define LDS_AT(base, row, o) ((const bf16x8*)((base) + (((row) * 128 + ((o) ^ (((row) & 7) << 4))) >> 1)))

#define READ_AB()                                                             \
  do {                                                                        \
    _Pragma("unroll") for (int f = 0; f < 4; ++f)                             \
      _Pragma("unroll") for (int ks = 0; ks < 2; ++ks) {                      \
        a[f][ks] = *LDS_AT(Ac, wm * 64 + f * 16 + li16, ks * 64 + hi4 * 16);  \
        b[f][ks] = *LDS_AT(Bc, wn * 64 + f * 16 + li16, ks * 64 + hi4 * 16);  \
      }                                                                       \
  } while (0)

#define MFMA_ALL()                                                            \
  do {                                                                        \
    __builtin_amdgcn_s_setprio(1);                                            \
    _Pragma("unroll") for (int ks = 0; ks < 2; ++ks)                          \
      _Pragma("unroll") for (int f = 0; f < 4; ++f)                           \
        _Pragma("unroll") for (int g = 0; g < 4; ++g)                         \
          acc[f][g] = __builtin_amdgcn_mfma_f32_16x16x32_bf16(                \
              a[f][ks], b[g][ks], acc[f][g], 0, 0, 0);                        \
    __builtin_amdgcn_s_setprio(0);                                            \
  } while (0)

// 128x128 tile, BK=64, 4 waves (2M x 2N), per-wave C = 64x64, NT=16 K-tiles.
// A and B each on 3-slot LDS rings (48 KiB total -> 2 blocks/CU): staging
// never targets a slot read by the current or next tile; one barrier +
// one counted vmcnt(8) per tile. Outstanding at tile-t end (new->old):
//   {A,B}(t+2)[8], {A,B}(t+1)[8] = 16 -> wait<=8 drains the t+1 set exactly.
// Slot safety: stage s2=(t+2)%3=(t-1)%3, whose ds_reads retired before the
// (t-1)-end barrier (MFMA consumed them pre-barrier). Read slot s0=t%3 landed
// at the (t-1)-end vmcnt(8) drain.
#define GEMM_PIPELINE()                                                       \
  do {                                                                        \
    stage_T(Ag, Asl[0], tid, 0); stage_T(Bg, Bsl[0], tid, 0);                 \
    stage_T(Ag, Asl[1], tid, 1); stage_T(Bg, Bsl[1], tid, 1);                 \
    WAIT_VM8();    /* tile-0 landed; tile-1's 8 stay in flight */             \
    BARRIER();                                                                \
    int s0 = 0, s2 = 2;                                                       \
    _Pragma("unroll 1") for (int t = 0; t < 16; ++t) {                        \
      stage_T(Ag, Asl[s2], tid, (t + 2) & 15);                                \
      stage_T(Bg, Bsl[s2], tid, (t + 2) & 15);                                \
      const unsigned short* Ac = Asl[s0];                                     \
      const unsigned short* Bc = Bsl[s0];                                     \
      READ_AB();                                                              \
      MFMA_ALL();                                                             \
      WAIT_VM8();                                                             \
      BARRIER();                                                              \
      s0 = (s0 == 2) ? 0 : s0 + 1;                                            \
      s2 = (s2 == 2) ? 0 : s2 + 1;                                            \
    }                                                                         \
  } while (0)

// ---------------------------------------------------------------------------
// prep: bf16-cast gq, gk, WK; scale WQ rows by Wmix[head] then cast.
// ---------------------------------------------------------------------------
__global__ void prep_kernel(const float* __restrict__ gq, const float* __restrict__ gk,
                            const float* __restrict__ WQ, const float* __restrict__ WK,
                            const float* __restrict__ Wmix,
                            unsigned short* __restrict__ gqb, unsigned short* __restrict__ gkb,
                            unsigned short* __restrict__ wqb, unsigned short* __restrict__ wkb) {
  const int NGQ = (B_ * TQ * E_) / 4;   // 1048576 vec4
  const int NW  = (E_ * E_) / 4;        // 262144 vec4
  const int total = 2 * NGQ + 2 * NW;
  for (int idx = blockIdx.x * blockDim.x + threadIdx.x; idx < total;
       idx += gridDim.x * blockDim.x) {
    const float4* src; unsigned short* dst; int local; float scale = 1.0f;
    if (idx < NGQ)            { src = (const float4*)gq; dst = gqb; local = idx; }
    else if (idx < 2 * NGQ)   { src = (const float4*)gk; dst = gkb; local = idx - NGQ; }
    else if (idx < 2*NGQ+NW)  { src = (const float4*)WQ; dst = wqb; local = idx - 2*NGQ;
                                scale = Wmix[local >> 14]; }   // vec4 idx -> row e = local/256, head = e/64
    else                      { src = (const float4*)WK; dst = wkb; local = idx - 2*NGQ - NW; }
    float4 v = src[local];
    ushort4 o;
    o.x = f2bf(v.x * scale); o.y = f2bf(v.y * scale);
    o.z = f2bf(v.z * scale); o.w = f2bf(v.w * scale);
    ((ushort4*)dst)[local] = o;
  }
}

// ---------------------------------------------------------------------------
// Projection GEMM: C[m,n] = sum_k A[m,k]*W[n,k]. 128x128 tile, 4 waves,
// A+B LDS rings, 2 blocks/CU. grid 512 (1-D, XCD rect decode).
// Per XCD (64 blocks): side=xcd>>2, rect=xcd&3 -> 8 mt x 8 nt = 2+2 MB = L2.
// ---------------------------------------------------------------------------
__global__ __launch_bounds__(256, 2) void proj_kernel(
    const unsigned short* __restrict__ gqb, const unsigned short* __restrict__ gkb,
    const unsigned short* __restrict__ wqb, const unsigned short* __restrict__ wkb,
    unsigned short* __restrict__ qp, unsigned short* __restrict__ kp) {
  __shared__ __align__(16) unsigned short Asl[3][8192];    // 3 x (128x64) = 24 KiB
  __shared__ __align__(16) unsigned short Bsl[3][8192];    // 3 x (128x64) = 24 KiB
  const int g_  = blockIdx.x;
  const int xcd = g_ & 7, j = g_ >> 3;      // j in 0..63
  const int side = xcd >> 2, r_ = xcd & 3;
  const int mt = r_ * 8 + (j & 7);          // 0..31  (32 x 128 = 4096 rows)
  const int nt = j >> 3;                    // 0..7
  const int m0 = mt * 128, n0 = nt * 128;
  const unsigned short* Ag = (side ? gkb : gqb) + (size_t)m0 * E_;
  const unsigned short* Bg = (side ? wkb : wqb) + (size_t)n0 * E_;
  unsigned short* C        = (side ? kp  : qp);
  const int tid = threadIdx.x, wave = tid >> 6, lane = tid & 63;
  const int wm = wave >> 1, wn = wave & 1, li16 = lane & 15, hi4 = lane >> 4;
  f32x4 acc[4][4] = {};
  bf16x8 a[4][2];
  bf16x8 b[4][2];
  GEMM_PIPELINE();
#pragma unroll
  for (int f = 0; f < 4; ++f)
#pragma unroll
    for (int g = 0; g < 4; ++g)
#pragma unroll
      for (int j2 = 0; j2 < 4; ++j2) {
        int row = m0 + wm * 64 + f * 16 + hi4 * 4 + j2;
        int col = n0 + wn * 64 + g * 16 + li16;
        C[(size_t)row * E_ + col] = f2bf(acc[f][g][j2]);
      }
  WAIT_VM0();   // drain wrapped tail stages before endpgm
}

// ---------------------------------------------------------------------------
// Score GEMM + fused partial logsumexp. 128x128 tile, 4 waves, rings, 2/CU.
// grid 512 (1-D). XCD rect: bb=xcd>>2, rect=xcd&3 ->
// qt in [(r&1)*8,+8), kt in [(r>>1)*8,+8); per-XCD set 2+2 MB = L2-fit.
// partials stride 16 (kt 0..15).
// ---------------------------------------------------------------------------
__global__ __launch_bounds__(256, 2) void score_lse_kernel(
    const unsigned short* __restrict__ qp, const unsigned short* __restrict__ kp,
    float2* __restrict__ partials) {
  __shared__ __align__(16) unsigned short Asl[3][8192];
  __shared__ __align__(16) unsigned short Bsl[3][8192];
  __shared__ float redM[2][128];
  __shared__ float redS[2][128];
  const int g_  = blockIdx.x;
  const int xcd = g_ & 7, j = g_ >> 3;      // j in 0..63
  const int bb = xcd >> 2, r_ = xcd & 3;
  const int qt = (r_ & 1) * 8 + (j & 7);    // 0..15
  const int kt = (r_ >> 1) * 8 + (j >> 3);  // 0..15
  const int m0 = qt * 128, n0 = kt * 128;
  const unsigned short* Ag = qp + (size_t)bb * TQ * E_ + (size_t)m0 * E_;
  const unsigned short* Bg = kp + (size_t)bb * TK * E_ + (size_t)n0 * E_;
  const int tid = threadIdx.x, wave = tid >> 6, lane = tid & 63;
  const int wm = wave >> 1, wn = wave & 1, li16 = lane & 15, hi4 = lane >> 4;
  f32x4 acc[4][4] = {};
  bf16x8 a[4][2];
  bf16x8 b[4][2];
  GEMM_PIPELINE();
  // ---- per-row LSE partial over this block's 128 cols ----
  // lane holds rows wm*64 + f*16 + hi4*4 + j2 ; cols wn*64 + g*16 + li16
#pragma unroll
  for (int f = 0; f < 4; ++f) {
#pragma unroll
    for (int j2 = 0; j2 < 4; ++j2) {
      float m = fmaxf(fmaxf(acc[f][0][j2], acc[f][1][j2]),
                      fmaxf(acc[f][2][j2], acc[f][3][j2]));
#pragma unroll
      for (int msk = 1; msk < 16; msk <<= 1) m = fmaxf(m, __shfl_xor(m, msk, 64));
      float s = 0.f;
#pragma unroll
      for (int g = 0; g < 4; ++g) s += expf(acc[f][g][j2] - m);
#pragma unroll
      for (int msk = 1; msk < 16; msk <<= 1) s += __shfl_xor(s, msk, 64);
      if (li16 == 0) {
        int row = wm * 64 + f * 16 + hi4 * 4 + j2;   // 0..127 unique per (wm,f,hi4,j2)
        redM[wn][row] = m;
        redS[wn][row] = s;
      }
    }
  }
  __syncthreads();   // drains pending tail stages + makes red[] visible
  if (tid < 128) {
    float mA = redM[0][tid], mB = redM[1][tid];
    float M = fmaxf(mA, mB);
    float S = redS[0][tid] * expf(mA - M) + redS[1][tid] * expf(mB - M);
    int qrow = bb * TQ + m0 + tid;
    partials[(size_t)qrow * 16 + kt] = make_float2(M, S);
  }
}

// ---------------------------------------------------------------------------
// finalize: combine 16 (m,s) partials per q-row -> logsumexp
// ---------------------------------------------------------------------------
__global__ void finalize_kernel(const float2* __restrict__ partials, float* __restrict__ out) {
  int r = blockIdx.x * blockDim.x + threadIdx.x;
  if (r >= MTOT) return;
  const float2* p = partials + (size_t)r * 16;
  float M = p[0].x;
#pragma unroll
  for (int i = 1; i < 16; ++i) M = fmaxf(M, p[i].x);
  float S = 0.f;
#pragma unroll
  for (int i = 0; i < 16; ++i) S += p[i].y * expf(p[i].x - M);
  out[r] = logf(S) + M;
}

// ---------------------------------------------------------------------------
extern "C" void kernel_launch(void* const* d_in, const int* in_sizes, int n_in,
                              void* d_out, int out_size, void* d_ws, size_t ws_size,
                              hipStream_t stream) {
  const float* gq   = (const float*)d_in[0];
  const float* gk   = (const float*)d_in[1];
  const float* WQ   = (const float*)d_in[2];
  const float* WK   = (const float*)d_in[3];
  const float* Wmix = (const float*)d_in[4];
  float* out = (float*)d_out;

  char* ws = (char*)d_ws;
  unsigned short* gqb = (unsigned short*)(ws);                 // 8 MiB
  unsigned short* gkb = (unsigned short*)(ws + 8388608);       // 8 MiB
  unsigned short* wqb = (unsigned short*)(ws + 16777216);      // 2 MiB
  unsigned short* wkb = (unsigned short*)(ws + 18874368);      // 2 MiB
  unsigned short* qp  = (unsigned short*)(ws + 20971520);      // 8 MiB
  unsigned short* kp  = (unsigned short*)(ws + 29360128);      // 8 MiB
  float2* partials    = (float2*)(ws + 37748736);              // 512 KiB

  hipLaunchKernelGGL(prep_kernel, dim3(1024), dim3(256), 0, stream,
                     gq, gk, WQ, WK, Wmix, gqb, gkb, wqb, wkb);
  hipLaunchKernelGGL(proj_kernel, dim3(512), dim3(256), 0, stream,
                     gqb, gkb, wqb, wkb, qp, kp);
  hipLaunchKernelGGL(score_lse_kernel, dim3(512), dim3(256), 0, stream,
                     qp, kp, partials);
  hipLaunchKernelGGL(finalize_kernel, dim3(16), dim3(256), 0, stream,
                     partials, out);
}

// Round 12
// 136.374 us; speedup vs baseline: 1.2847x; 1.2603x over previous
//
#include <hip/hip_runtime.h>
#include <hip/hip_bf16.h>
#include <math.h>

// Problem constants (AttentionSynapse): B=2, Tq=Tk=2048, E=Eq=Ek=1024, H=16, D=64
#define B_    2
#define TQ    2048
#define TK    2048
#define E_    1024
#define MTOT  4096   // B*TQ

typedef __attribute__((ext_vector_type(8))) short bf16x8;
typedef __attribute__((ext_vector_type(4))) float f32x4;

__device__ __forceinline__ unsigned short f2bf(float x) {
  unsigned int u = __float_as_uint(x);
  u += 0x7fff + ((u >> 16) & 1);      // round-to-nearest-even
  return (unsigned short)(u >> 16);
}

__device__ __forceinline__ void load_lds16(const void* g, void* l) {
  // async global->LDS, 16B/lane; LDS dest = wave-uniform base + lane*16
  __builtin_amdgcn_global_load_lds(
      (const __attribute__((address_space(1))) unsigned int*)g,
      (__attribute__((address_space(3))) unsigned int*)l, 16, 0, 0);
}

#define BARRIER() do { asm volatile("" ::: "memory"); __builtin_amdgcn_s_barrier(); asm volatile("" ::: "memory"); } while (0)
#define WAIT_VM0()   asm volatile("s_waitcnt vmcnt(0)" ::: "memory")

// ---------------------------------------------------------------------------
// Tile stage: 128 rows x 64 cols bf16 (16 KiB), 256 threads x 4 gload_lds.
// T2 swizzle: logical (row, byte o) -> LDS byte row*128 + (o ^ ((row&7)<<4));
// LDS dest linear, global source col pre-XOR'd (involution), read applies XOR.
// ---------------------------------------------------------------------------
__device__ __forceinline__ void stage_T(const unsigned short* gsrc, unsigned short* lds,
                                        int tid, int kt) {
  const int r  = tid >> 3;                          // 0..31
  const int c8 = ((tid & 7) ^ (r & 7)) * 8;         // pre-swizzled col (elems)
  const unsigned short* g = gsrc + (size_t)r * E_ + (size_t)kt * 64 + c8;
  unsigned short* l = lds + tid * 8;
#pragma unroll
  for (int i = 0; i < 4; ++i)                       // rows r, r+32, r+64, r+96
    load_lds16(g + (size_t)(32 * i) * E_, l + 2048 * i);
}

// Swizzled LDS read address (elems): row in tile, o = byte offset in row
#define LDS_AT(base, row, o) ((const bf16x8*)((base) + (((row) * 128 + ((o) ^ (((row) & 7) << 4))) >> 1)))

#define READ_AB()                                                             \
  do {                                                                        \
    _Pragma("unroll") for (int f = 0; f < 4; ++f)                             \
      _Pragma("unroll") for (int ks = 0; ks < 2; ++ks) {                      \
        a[f][ks] = *LDS_AT(Ac, wm * 64 + f * 16 + li16, ks * 64 + hi4 * 16);  \
        b[f][ks] = *LDS_AT(Bc, wn * 64 + f * 16 + li16, ks * 64 + hi4 * 16);  \
      }                                                                       \
  } while (0)

#define MFMA_ALL()                                                            \
  do {                                                                        \
    __builtin_amdgcn_s_setprio(1);                                            \
    _Pragma("unroll") for (int ks = 0; ks < 2; ++ks)                          \
      _Pragma("unroll") for (int f = 0; f < 4; ++f)                           \
        _Pragma("unroll") for (int g = 0; g < 4; ++g)                         \
          acc[f][g] = __builtin_amdgcn_mfma_f32_16x16x32_bf16(                \
              a[f][ks], b[g][ks], acc[f][g], 0, 0, 0);                        \
    __builtin_amdgcn_s_setprio(0);                                            \
  } while (0)

// 128x128 tile, BK=64, 4 waves (2M x 2N), per-wave C = 64x64, NT=16 K-tiles.
// T3 minimum 2-phase (guide §5.5 recipe): per tile, issue STAGE(t+1 ->
// buf[c^1]) FIRST, then ds_read buf[c] + MFMA, then one vmcnt(0)+barrier.
// Dbuf slot safety: buf[c^1]'s tile-(t-1) ds_reads retired before the
// (t-1)-end barrier, so staging into it during tile t is race-free.
// LDS = 2x16 + 2x16 = 64 KiB -> 2 blocks/CU (the TLP that fills the drain).
#define GEMM_PIPELINE()                                                       \
  do {                                                                        \
    stage_T(Ag, Asl[0], tid, 0); stage_T(Bg, Bsl[0], tid, 0);                 \
    WAIT_VM0();                                                               \
    BARRIER();                                                                \
    _Pragma("unroll 1") for (int t = 0; t < 16; ++t) {                        \
      const int c = t & 1;                                                    \
      if (t < 15) {                                                           \
        stage_T(Ag, Asl[c ^ 1], tid, t + 1);                                  \
        stage_T(Bg, Bsl[c ^ 1], tid, t + 1);                                  \
      }                                                                       \
      const unsigned short* Ac = Asl[c];                                      \
      const unsigned short* Bc = Bsl[c];                                      \
      READ_AB();                                                              \
      MFMA_ALL();                                                             \
      WAIT_VM0();                                                             \
      BARRIER();                                                              \
    }                                                                         \
  } while (0)

// ---------------------------------------------------------------------------
// prep: bf16-cast gq, gk, WK; scale WQ rows by Wmix[head] then cast.
// ---------------------------------------------------------------------------
__global__ void prep_kernel(const float* __restrict__ gq, const float* __restrict__ gk,
                            const float* __restrict__ WQ, const float* __restrict__ WK,
                            const float* __restrict__ Wmix,
                            unsigned short* __restrict__ gqb, unsigned short* __restrict__ gkb,
                            unsigned short* __restrict__ wqb, unsigned short* __restrict__ wkb) {
  const int NGQ = (B_ * TQ * E_) / 4;   // 1048576 vec4
  const int NW  = (E_ * E_) / 4;        // 262144 vec4
  const int total = 2 * NGQ + 2 * NW;
  for (int idx = blockIdx.x * blockDim.x + threadIdx.x; idx < total;
       idx += gridDim.x * blockDim.x) {
    const float4* src; unsigned short* dst; int local; float scale = 1.0f;
    if (idx < NGQ)            { src = (const float4*)gq; dst = gqb; local = idx; }
    else if (idx < 2 * NGQ)   { src = (const float4*)gk; dst = gkb; local = idx - NGQ; }
    else if (idx < 2*NGQ+NW)  { src = (const float4*)WQ; dst = wqb; local = idx - 2*NGQ;
                                scale = Wmix[local >> 14]; }   // vec4 idx -> row e = local/256, head = e/64
    else                      { src = (const float4*)WK; dst = wkb; local = idx - 2*NGQ - NW; }
    float4 v = src[local];
    ushort4 o;
    o.x = f2bf(v.x * scale); o.y = f2bf(v.y * scale);
    o.z = f2bf(v.z * scale); o.w = f2bf(v.w * scale);
    ((ushort4*)dst)[local] = o;
  }
}

// ---------------------------------------------------------------------------
// Projection GEMM: C[m,n] = sum_k A[m,k]*W[n,k]. 128x128 tile, 4 waves,
// A+B LDS dbuf, 2 blocks/CU. grid 512 (1-D, XCD rect decode).
// Per XCD (64 blocks): side=xcd>>2, rect=xcd&3 -> 8 mt x 8 nt = 2+2 MB = L2.
// ---------------------------------------------------------------------------
__global__ __launch_bounds__(256, 2) void proj_kernel(
    const unsigned short* __restrict__ gqb, const unsigned short* __restrict__ gkb,
    const unsigned short* __restrict__ wqb, const unsigned short* __restrict__ wkb,
    unsigned short* __restrict__ qp, unsigned short* __restrict__ kp) {
  __shared__ __align__(16) unsigned short Asl[2][8192];    // 2 x 16 KiB
  __shared__ __align__(16) unsigned short Bsl[2][8192];    // 2 x 16 KiB
  const int g_  = blockIdx.x;
  const int xcd = g_ & 7, j = g_ >> 3;      // j in 0..63
  const int side = xcd >> 2, r_ = xcd & 3;
  const int mt = r_ * 8 + (j & 7);          // 0..31  (32 x 128 = 4096 rows)
  const int nt = j >> 3;                    // 0..7
  const int m0 = mt * 128, n0 = nt * 128;
  const unsigned short* Ag = (side ? gkb : gqb) + (size_t)m0 * E_;
  const unsigned short* Bg = (side ? wkb : wqb) + (size_t)n0 * E_;
  unsigned short* C        = (side ? kp  : qp);
  const int tid = threadIdx.x, wave = tid >> 6, lane = tid & 63;
  const int wm = wave >> 1, wn = wave & 1, li16 = lane & 15, hi4 = lane >> 4;
  f32x4 acc[4][4] = {};
  bf16x8 a[4][2];
  bf16x8 b[4][2];
  GEMM_PIPELINE();
#pragma unroll
  for (int f = 0; f < 4; ++f)
#pragma unroll
    for (int g = 0; g < 4; ++g)
#pragma unroll
      for (int j2 = 0; j2 < 4; ++j2) {
        int row = m0 + wm * 64 + f * 16 + hi4 * 4 + j2;
        int col = n0 + wn * 64 + g * 16 + li16;
        C[(size_t)row * E_ + col] = f2bf(acc[f][g][j2]);
      }
}

// ---------------------------------------------------------------------------
// Score GEMM + fused partial logsumexp. 128x128 tile, 4 waves, dbuf, 2/CU.
// grid 512 (1-D). XCD rect: bb=xcd>>2, rect=xcd&3 ->
// qt in [(r&1)*8,+8), kt in [(r>>1)*8,+8); per-XCD set 2+2 MB = L2-fit.
// partials stride 16 (kt 0..15).
// ---------------------------------------------------------------------------
__global__ __launch_bounds__(256, 2) void score_lse_kernel(
    const unsigned short* __restrict__ qp, const unsigned short* __restrict__ kp,
    float2* __restrict__ partials) {
  __shared__ __align__(16) unsigned short Asl[2][8192];
  __shared__ __align__(16) unsigned short Bsl[2][8192];
  __shared__ float redM[2][128];
  __shared__ float redS[2][128];
  const int g_  = blockIdx.x;
  const int xcd = g_ & 7, j = g_ >> 3;      // j in 0..63
  const int bb = xcd >> 2, r_ = xcd & 3;
  const int qt = (r_ & 1) * 8 + (j & 7);    // 0..15
  const int kt = (r_ >> 1) * 8 + (j >> 3);  // 0..15
  const int m0 = qt * 128, n0 = kt * 128;
  const unsigned short* Ag = qp + (size_t)bb * TQ * E_ + (size_t)m0 * E_;
  const unsigned short* Bg = kp + (size_t)bb * TK * E_ + (size_t)n0 * E_;
  const int tid = threadIdx.x, wave = tid >> 6, lane = tid & 63;
  const int wm = wave >> 1, wn = wave & 1, li16 = lane & 15, hi4 = lane >> 4;
  f32x4 acc[4][4] = {};
  bf16x8 a[4][2];
  bf16x8 b[4][2];
  GEMM_PIPELINE();
  // ---- per-row LSE partial over this block's 128 cols ----
  // lane holds rows wm*64 + f*16 + hi4*4 + j2 ; cols wn*64 + g*16 + li16
#pragma unroll
  for (int f = 0; f < 4; ++f) {
#pragma unroll
    for (int j2 = 0; j2 < 4; ++j2) {
      float m = fmaxf(fmaxf(acc[f][0][j2], acc[f][1][j2]),
                      fmaxf(acc[f][2][j2], acc[f][3][j2]));
#pragma unroll
      for (int msk = 1; msk < 16; msk <<= 1) m = fmaxf(m, __shfl_xor(m, msk, 64));
      float s = 0.f;
#pragma unroll
      for (int g = 0; g < 4; ++g) s += expf(acc[f][g][j2] - m);
#pragma unroll
      for (int msk = 1; msk < 16; msk <<= 1) s += __shfl_xor(s, msk, 64);
      if (li16 == 0) {
        int row = wm * 64 + f * 16 + hi4 * 4 + j2;   // 0..127 unique per (wm,f,hi4,j2)
        redM[wn][row] = m;
        redS[wn][row] = s;
      }
    }
  }
  __syncthreads();   // makes red[] visible
  if (tid < 128) {
    float mA = redM[0][tid], mB = redM[1][tid];
    float M = fmaxf(mA, mB);
    float S = redS[0][tid] * expf(mA - M) + redS[1][tid] * expf(mB - M);
    int qrow = bb * TQ + m0 + tid;
    partials[(size_t)qrow * 16 + kt] = make_float2(M, S);
  }
}

// ---------------------------------------------------------------------------
// finalize: combine 16 (m,s) partials per q-row -> logsumexp
// ---------------------------------------------------------------------------
__global__ void finalize_kernel(const float2* __restrict__ partials, float* __restrict__ out) {
  int r = blockIdx.x * blockDim.x + threadIdx.x;
  if (r >= MTOT) return;
  const float2* p = partials + (size_t)r * 16;
  float M = p[0].x;
#pragma unroll
  for (int i = 1; i < 16; ++i) M = fmaxf(M, p[i].x);
  float S = 0.f;
#pragma unroll
  for (int i = 0; i < 16; ++i) S += p[i].y * expf(p[i].x - M);
  out[r] = logf(S) + M;
}

// ---------------------------------------------------------------------------
extern "C" void kernel_launch(void* const* d_in, const int* in_sizes, int n_in,
                              void* d_out, int out_size, void* d_ws, size_t ws_size,
                              hipStream_t stream) {
  const float* gq   = (const float*)d_in[0];
  const float* gk   = (const float*)d_in[1];
  const float* WQ   = (const float*)d_in[2];
  const float* WK   = (const float*)d_in[3];
  const float* Wmix = (const float*)d_in[4];
  float* out = (float*)d_out;

  char* ws = (char*)d_ws;
  unsigned short* gqb = (unsigned short*)(ws);                 // 8 MiB
  unsigned short* gkb = (unsigned short*)(ws + 8388608);       // 8 MiB
  unsigned short* wqb = (unsigned short*)(ws + 16777216);      // 2 MiB
  unsigned short* wkb = (unsigned short*)(ws + 18874368);      // 2 MiB
  unsigned short* qp  = (unsigned short*)(ws + 20971520);      // 8 MiB
  unsigned short* kp  = (unsigned short*)(ws + 29360128);      // 8 MiB
  float2* partials    = (float2*)(ws + 37748736);              // 512 KiB

  hipLaunchKernelGGL(prep_kernel, dim3(1024), dim3(256), 0, stream,
                     gq, gk, WQ, WK, Wmix, gqb, gkb, wqb, wkb);
  hipLaunchKernelGGL(proj_kernel, dim3(512), dim3(256), 0, stream,
                     gqb, gkb, wqb, wkb, qp, kp);
  hipLaunchKernelGGL(score_lse_kernel, dim3(512), dim3(256), 0, stream,
                     qp, kp, partials);
  hipLaunchKernelGGL(finalize_kernel, dim3(16), dim3(256), 0, stream,
                     partials, out);
}